// Round 13
// baseline (116.897 us; speedup 1.0000x reference)
//
#include <hip/hip_runtime.h>

typedef unsigned short u16;
typedef float f32x4 __attribute__((ext_vector_type(4)));
typedef __bf16 bf16x8 __attribute__((ext_vector_type(8)));
typedef unsigned int u32x4 __attribute__((ext_vector_type(4)));
typedef u16 u16x4 __attribute__((ext_vector_type(4)));
typedef u16 u16x8 __attribute__((ext_vector_type(8)));

static __device__ __forceinline__ u16 f2bf(float f) {
  union { __bf16 h; u16 u; } c;
  c.h = (__bf16)f;
  return c.u;
}

static __device__ __forceinline__ void gload_lds16(const void* g, void* l) {
  __builtin_amdgcn_global_load_lds(
      (const __attribute__((address_space(1))) unsigned int*)g,
      (__attribute__((address_space(3))) unsigned int*)l, 16, 0, 0);
}

// ---------------- fused fp32 -> bf16 convert ----------------
__global__ __launch_bounds__(256) void cvt3_f32_bf16(const float* __restrict__ a,
                                                     const float* __restrict__ bb,
                                                     const float* __restrict__ cc,
                                                     u16* __restrict__ out,
                                                     int n1, int n2, int n3) {
  int i = blockIdx.x * 256 + threadIdx.x;
  const float* src;
  int j = i;
  if (i < n1) { src = a; }
  else if (i < n1 + n2) { src = bb; j = i - n1; }
  else { src = cc; j = i - n1 - n2; if (j >= n3) return; }
  f32x4 v = *((const f32x4*)src + j);
  u16x4 o;
  o[0] = f2bf(v[0]); o[1] = f2bf(v[1]); o[2] = f2bf(v[2]); o[3] = f2bf(v[3]);
  *((u16x4*)out + i) = o;
}

// ---------------- 128x128 GEMM (proven m97-structure) — used for proj ----------------
template<int OUT_BF16, int FUSE_VT>
__global__ __launch_bounds__(256) void gemm_nt(const u16* __restrict__ A,
                                               const u16* __restrict__ B,
                                               void* __restrict__ Cp,
                                               u16* __restrict__ vt,
                                               int M, int N, int K, int gy) {
  __shared__ __align__(16) u16 lA[128 * 64];
  __shared__ __align__(16) u16 lB[128 * 64];
  const int tid = threadIdx.x;
  const int lane = tid & 63;
  const int wave = tid >> 6;
  const int wm = wave >> 1, wn = wave & 1;
  const int l15 = lane & 15, lg = lane >> 4;

  const int bid = blockIdx.x;
  const int xcd = bid & 7, s = bid >> 3;
  const int pnx = (N >> 7) >> 3;
  const int bm = (s % gy) * 128;
  const int bn = (xcd * pnx + s / gy) * 128;

  f32x4 acc[4][4];
#pragma unroll
  for (int i = 0; i < 4; ++i)
#pragma unroll
    for (int j = 0; j < 4; ++j) acc[i][j] = (f32x4){0.f, 0.f, 0.f, 0.f};

  const u16* Ag[4];
  const u16* Bg[4];
#pragma unroll
  for (int it = 0; it < 4; ++it) {
    const int ss = it * 256 + tid;
    const int row = ss >> 3, g = ss & 7;
    const int gsw = g ^ (row & 7);
    Ag[it] = A + (size_t)(bm + row) * K + gsw * 8;
    Bg[it] = B + (size_t)(bn + row) * K + gsw * 8;
  }

  for (int k0 = 0; k0 < K; k0 += 64) {
#pragma unroll
    for (int it = 0; it < 4; ++it) {
      gload_lds16(Ag[it] + k0, (u16*)lA + (size_t)(it * 256 + tid) * 8);
      gload_lds16(Bg[it] + k0, (u16*)lB + (size_t)(it * 256 + tid) * 8);
    }
    __syncthreads();
#pragma unroll
    for (int kk = 0; kk < 2; ++kk) {
      bf16x8 af[4], bfv[4];
#pragma unroll
      for (int mf = 0; mf < 4; ++mf) {
        const int row = wm * 64 + mf * 16 + l15;
        af[mf] = *(const bf16x8*)((const char*)lA + row * 128 +
                                  ((kk * 64 + lg * 16) ^ ((row & 7) << 4)));
      }
#pragma unroll
      for (int nf = 0; nf < 4; ++nf) {
        const int row = wn * 64 + nf * 16 + l15;
        bfv[nf] = *(const bf16x8*)((const char*)lB + row * 128 +
                                   ((kk * 64 + lg * 16) ^ ((row & 7) << 4)));
      }
#pragma unroll
      for (int mf = 0; mf < 4; ++mf)
#pragma unroll
        for (int nf = 0; nf < 4; ++nf)
          acc[mf][nf] = __builtin_amdgcn_mfma_f32_16x16x32_bf16(af[mf], bfv[nf], acc[mf][nf], 0, 0, 0);
    }
    __syncthreads();
  }

  if (FUSE_VT && bn >= 2048) {
#pragma unroll
    for (int mf = 0; mf < 4; ++mf) {
      const int row0 = bm + wm * 64 + mf * 16 + lg * 4;
      const int b = row0 >> 11, t0 = row0 & 2047;
#pragma unroll
      for (int nf = 0; nf < 4; ++nf) {
        const int colv = bn - 2048 + wn * 64 + nf * 16 + l15;
        const int h = colv >> 6, d = colv & 63;
        u16x4 pk;
        pk[0] = f2bf(acc[mf][nf][0]); pk[1] = f2bf(acc[mf][nf][1]);
        pk[2] = f2bf(acc[mf][nf][2]); pk[3] = f2bf(acc[mf][nf][3]);
        *(u16x4*)&vt[((size_t)((b * 16 + h) * 64 + d)) * 2048 + t0] = pk;
      }
    }
  } else {
#pragma unroll
    for (int mf = 0; mf < 4; ++mf) {
#pragma unroll
      for (int r = 0; r < 4; ++r) {
        const int row = bm + wm * 64 + mf * 16 + lg * 4 + r;
#pragma unroll
        for (int nf = 0; nf < 4; ++nf) {
          const int col = bn + wn * 64 + nf * 16 + l15;
          const float v = acc[mf][nf][r];
          if (OUT_BF16) ((u16*)Cp)[(size_t)row * N + col] = f2bf(v);
          else          ((float*)Cp)[(size_t)row * N + col] = v;
        }
      }
    }
  }
}

// ---------------- 256x256 8-phase GEMM (m201-style port) — used for qkv ----------------
// 512 thr (8 waves 2Mx4N), BK=64, 2 K-tiles/iter, LDS 128KB (buf0/buf1, each
// A 32KB + B 32KB). Per phase: {ds_reads; half-tile stage (2 gload_lds);
// raw s_barrier; setprio(1) 16 MFMA setprio(0); [vmcnt gate]; raw s_barrier}.
// vmcnt(4) before the closing barriers of phases 4/8; last iter vmcnt(0).
// Stage slots: ph0 A0(b1,k1); ph1 A1(b1,k1)+B0(b0,k0+2); ph2 B1(b0,k0+2);
// ph4 A0(b0,k0+2); ph5 A1(b0,k0+2)+B0(b1,k1+2); ph6 B1(b1,k1+2).
template<int OUT_BF16, int FUSE_VT>
__global__ __launch_bounds__(512, 2) void gemm256(const u16* __restrict__ A,
                                                  const u16* __restrict__ B,
                                                  void* __restrict__ Cp,
                                                  u16* __restrict__ vt,
                                                  int M, int N, int K) {
  __shared__ __align__(16) u16 shm[65536];  // 128 KB
  const int tid = threadIdx.x;
  const int lane = tid & 63, wave = tid >> 6;
  const int wm = wave >> 2, wn = wave & 3;
  const int l15 = lane & 15, lg = lane >> 4;

  const int bid = blockIdx.x;
  const int g = (bid & 7) * ((int)gridDim.x >> 3) + (bid >> 3);
  const int bm = (g & 15) * 256;      // M/256 = 16 tiles (m-major)
  const int bn = (g >> 4) * 256;

  // staging precompute: 2 chunks of 16B per thread per half-tile
  size_t srcA[2][2], srcB[2][2];      // [i][half]
  int lo[2];
#pragma unroll
  for (int i = 0; i < 2; ++i) {
    const int flat = i * 512 + tid;
    const int row = flat >> 3, gg = flat & 7;
    const int gsw = gg ^ (row & 7);   // inverse swizzle on global source
    lo[i] = flat * 16;                // linear LDS byte offset within half
#pragma unroll
    for (int half = 0; half < 2; ++half) {
      srcA[i][half] = (size_t)(bm + half * 128 + row) * K + gsw * 8;
      srcB[i][half] = (size_t)(bn + half * 128 + row) * K + gsw * 8;
    }
  }

#define STAGE_A(buf, half, kt)                                                     \
  do {                                                                             \
    gload_lds16(A + srcA[0][half] + (size_t)(kt) * 64,                             \
                (char*)shm + (buf) * 65536 + (half) * 16384 + lo[0]);              \
    gload_lds16(A + srcA[1][half] + (size_t)(kt) * 64,                             \
                (char*)shm + (buf) * 65536 + (half) * 16384 + lo[1]);              \
  } while (0)
#define STAGE_B(buf, half, kt)                                                     \
  do {                                                                             \
    gload_lds16(B + srcB[0][half] + (size_t)(kt) * 64,                             \
                (char*)shm + (buf) * 65536 + 32768 + (half) * 16384 + lo[0]);      \
    gload_lds16(B + srcB[1][half] + (size_t)(kt) * 64,                             \
                (char*)shm + (buf) * 65536 + 32768 + (half) * 16384 + lo[1]);      \
  } while (0)

  f32x4 acc[8][4];
#pragma unroll
  for (int i = 0; i < 8; ++i)
#pragma unroll
    for (int j = 0; j < 4; ++j) acc[i][j] = (f32x4){0.f, 0.f, 0.f, 0.f};

  // prologue: kt0 full + kt1 B-halves; wait kt0 (leave 4 outstanding); barrier
  STAGE_A(0, 0, 0); STAGE_A(0, 1, 0);
  STAGE_B(0, 0, 0); STAGE_B(0, 1, 0);
  STAGE_B(1, 0, 1); STAGE_B(1, 1, 1);
  asm volatile("s_waitcnt vmcnt(4)" ::: "memory");
  __builtin_amdgcn_s_barrier();
  __builtin_amdgcn_sched_barrier(0);

  const int NT2 = K / 128;  // iterations (2 K-tiles each)
#pragma unroll 1
  for (int t = 0; t < NT2; ++t) {
    const int k0 = 2 * t, k1 = 2 * t + 1;
    const bool more = (t < NT2 - 1);

#pragma unroll
    for (int grp = 0; grp < 2; ++grp) {         // grp 0: buf0/k0, grp 1: buf1/k1
      const char* Ab = (char*)shm + grp * 65536;
      const char* Bb = Ab + 32768;
      bf16x8 bB[4][2];
#pragma unroll
      for (int j = 0; j < 4; ++j) {
        // ---- ds reads ----
        if (j == 0) {
#pragma unroll
          for (int nn = 0; nn < 4; ++nn) {
            const int r = wn * 64 + nn * 16 + l15;
            const int x = (r & 7) << 4;
            bB[nn][0] = *(const bf16x8*)(Bb + r * 128 + ((lg * 16) ^ x));
            bB[nn][1] = *(const bf16x8*)(Bb + r * 128 + ((64 + lg * 16) ^ x));
          }
        }
        bf16x8 af[2][2];
#pragma unroll
        for (int mm = 0; mm < 2; ++mm) {
          const int r = wm * 128 + (2 * j + mm) * 16 + l15;
          const int x = (r & 7) << 4;
          af[mm][0] = *(const bf16x8*)(Ab + r * 128 + ((lg * 16) ^ x));
          af[mm][1] = *(const bf16x8*)(Ab + r * 128 + ((64 + lg * 16) ^ x));
        }
        // ---- stage slots ----
        if (grp == 0) {
          if (j == 0) { STAGE_A(1, 0, k1); }
          if (j == 1) { STAGE_A(1, 1, k1); if (more) STAGE_B(0, 0, k0 + 2); }
          if (j == 2) { if (more) STAGE_B(0, 1, k0 + 2); }
        } else {
          if (j == 0) { if (more) STAGE_A(0, 0, k0 + 2); }
          if (j == 1) { if (more) { STAGE_A(0, 1, k0 + 2); STAGE_B(1, 0, k1 + 2); } }
          if (j == 2) { if (more) STAGE_B(1, 1, k1 + 2); }
        }
        __builtin_amdgcn_s_barrier();
        __builtin_amdgcn_s_setprio(1);
#pragma unroll
        for (int mm = 0; mm < 2; ++mm)
#pragma unroll
          for (int nn = 0; nn < 4; ++nn) {
            acc[2 * j + mm][nn] = __builtin_amdgcn_mfma_f32_16x16x32_bf16(
                af[mm][0], bB[nn][0], acc[2 * j + mm][nn], 0, 0, 0);
            acc[2 * j + mm][nn] = __builtin_amdgcn_mfma_f32_16x16x32_bf16(
                af[mm][1], bB[nn][1], acc[2 * j + mm][nn], 0, 0, 0);
          }
        __builtin_amdgcn_s_setprio(0);
        if (j == 3) {                           // gate before closing barrier
          if (grp == 0) {
            if (more) asm volatile("s_waitcnt vmcnt(4)" ::: "memory");
            else      asm volatile("s_waitcnt vmcnt(0)" ::: "memory");
          } else if (more) {
            asm volatile("s_waitcnt vmcnt(4)" ::: "memory");
          }
        }
        __builtin_amdgcn_s_barrier();
        if (j == 3) __builtin_amdgcn_sched_barrier(0);
      }
    }
  }
#undef STAGE_A
#undef STAGE_B

  // epilogue
  if (FUSE_VT && bn >= 2048) {
#pragma unroll
    for (int m = 0; m < 8; ++m) {
      const int row0 = bm + wm * 128 + m * 16 + lg * 4;
      const int b = row0 >> 11, t0 = row0 & 2047;
#pragma unroll
      for (int nn = 0; nn < 4; ++nn) {
        const int colv = bn - 2048 + wn * 64 + nn * 16 + l15;
        const int h = colv >> 6, d = colv & 63;
        u16x4 pk;
        pk[0] = f2bf(acc[m][nn][0]); pk[1] = f2bf(acc[m][nn][1]);
        pk[2] = f2bf(acc[m][nn][2]); pk[3] = f2bf(acc[m][nn][3]);
        *(u16x4*)&vt[((size_t)((b * 16 + h) * 64 + d)) * 2048 + t0] = pk;
      }
    }
  } else {
#pragma unroll
    for (int m = 0; m < 8; ++m) {
#pragma unroll
      for (int r = 0; r < 4; ++r) {
        const int row = bm + wm * 128 + m * 16 + lg * 4 + r;
#pragma unroll
        for (int nn = 0; nn < 4; ++nn) {
          const int col = bn + wn * 64 + nn * 16 + l15;
          const float v = acc[m][nn][r];
          if (OUT_BF16) ((u16*)Cp)[(size_t)row * N + col] = f2bf(v);
          else          ((float*)Cp)[(size_t)row * N + col] = v;
        }
      }
    }
  }
}

// ---------------- flash attention fwd (causal) — proven R9 body ----------------
__global__ __launch_bounds__(256) void attn_fwd(const u16* __restrict__ qkv,
                                                const u16* __restrict__ vt,
                                                u16* __restrict__ y) {
  constexpr int T = 2048, C = 1024, C3 = 3072, D = 64, NQ = 32;
  __shared__ __align__(16) u16 lK[2][64 * 64];
  __shared__ __align__(16) u16 lV[2][64 * 64];
  __shared__ __align__(16) u16 lP[4 * 16 * 64];
  const int tid = threadIdx.x, lane = tid & 63, w = tid >> 6;
  const int l15 = lane & 15, lg = lane >> 4;

  const int bid = blockIdx.x;
  const int xcd = bid & 7, slot = bid >> 3;
  const int bh = xcd * 4 + (slot >> 4);
  const int pi = slot & 15;
  const int b = bh >> 4, h = bh & 15;

  const int r0 = tid >> 3, off0 = (tid & 7) * 8;
  const int r1 = (tid + 256) >> 3;
  const int sb0 = (off0 * 2) ^ ((r0 & 7) << 4);
  const int sb1 = (off0 * 2) ^ ((r1 & 7) << 4);
  const u16* Kbase = qkv + (size_t)b * T * C3 + C + h * D;
  const u16* Vbase = vt + (size_t)bh * D * T;

  const float qscale = 0.125f * 1.44269504088896f;

#pragma unroll 1
  for (int qi = 0; qi < 2; ++qi) {
    const int qt = (qi == 0) ? pi : (NQ - 1 - pi);
    const int q0 = qt * 64;

    const size_t qoff = ((size_t)b * T + q0 + w * 16 + l15) * C3 + h * D;
    const bf16x8 aq0 = *(const bf16x8*)&qkv[qoff + lg * 8];
    const bf16x8 aq1 = *(const bf16x8*)&qkv[qoff + 32 + lg * 8];

    float m = -1.0e30f, l = 0.f;
    f32x4 o_acc[4];
#pragma unroll
    for (int nf = 0; nf < 4; ++nf) o_acc[nf] = (f32x4){0.f, 0.f, 0.f, 0.f};

    u32x4 rk0 = *(const u32x4*)(Kbase + (size_t)r0 * C3 + off0);
    u32x4 rk1 = *(const u32x4*)(Kbase + (size_t)r1 * C3 + off0);
    u32x4 rv0 = *(const u32x4*)(Vbase + (size_t)r0 * T + off0);
    u32x4 rv1 = *(const u32x4*)(Vbase + (size_t)r1 * T + off0);
    __syncthreads();
    *(u32x4*)&lK[0][(r0 * 128 + sb0) >> 1] = rk0;
    *(u32x4*)&lK[0][(r1 * 128 + sb1) >> 1] = rk1;
    *(u32x4*)&lV[0][(r0 * 128 + sb0) >> 1] = rv0;
    *(u32x4*)&lV[0][(r1 * 128 + sb1) >> 1] = rv1;
    if (qt > 0) {
      rk0 = *(const u32x4*)(Kbase + (size_t)(64 + r0) * C3 + off0);
      rk1 = *(const u32x4*)(Kbase + (size_t)(64 + r1) * C3 + off0);
      rv0 = *(const u32x4*)(Vbase + (size_t)r0 * T + 64 + off0);
      rv1 = *(const u32x4*)(Vbase + (size_t)r1 * T + 64 + off0);
    }

    for (int kt = 0; kt <= qt; ++kt) {
      const int cur = kt & 1;
      __syncthreads();
      if (kt < qt) {
        *(u32x4*)&lK[cur ^ 1][(r0 * 128 + sb0) >> 1] = rk0;
        *(u32x4*)&lK[cur ^ 1][(r1 * 128 + sb1) >> 1] = rk1;
        *(u32x4*)&lV[cur ^ 1][(r0 * 128 + sb0) >> 1] = rv0;
        *(u32x4*)&lV[cur ^ 1][(r1 * 128 + sb1) >> 1] = rv1;
        if (kt + 1 < qt) {
          const int kn = (kt + 2) * 64;
          rk0 = *(const u32x4*)(Kbase + (size_t)(kn + r0) * C3 + off0);
          rk1 = *(const u32x4*)(Kbase + (size_t)(kn + r1) * C3 + off0);
          rv0 = *(const u32x4*)(Vbase + (size_t)r0 * T + kn + off0);
          rv1 = *(const u32x4*)(Vbase + (size_t)r1 * T + kn + off0);
        }
      }
      const u16* Kc = lK[cur];
      const u16* Vc = lV[cur];

      f32x4 s[4];
#pragma unroll
      for (int nf = 0; nf < 4; ++nf) s[nf] = (f32x4){0.f, 0.f, 0.f, 0.f};
      __builtin_amdgcn_s_setprio(1);
#pragma unroll
      for (int nf = 0; nf < 4; ++nf) {
        const int row = nf * 16 + l15;
        const int x = (row & 7) << 4;
        bf16x8 bk0 = *(const bf16x8*)&Kc[(row * 128 + ((lg * 16) ^ x)) >> 1];
        bf16x8 bk1 = *(const bf16x8*)&Kc[(row * 128 + ((64 + lg * 16) ^ x)) >> 1];
        s[nf] = __builtin_amdgcn_mfma_f32_16x16x32_bf16(bk0, aq0, s[nf], 0, 0, 0);
        s[nf] = __builtin_amdgcn_mfma_f32_16x16x32_bf16(bk1, aq1, s[nf], 0, 0, 0);
      }
      __builtin_amdgcn_s_setprio(0);

#pragma unroll
      for (int nf = 0; nf < 4; ++nf) {
#pragma unroll
        for (int r = 0; r < 4; ++r) {
          float v = s[nf][r] * qscale;
          if (kt == qt) {
            if (nf * 16 + lg * 4 + r > w * 16 + l15) v = -1.0e30f;
          }
          s[nf][r] = v;
        }
      }

      float t0a = fmaxf(fmaxf(s[0][0], s[0][1]), fmaxf(s[0][2], s[0][3]));
      float t1a = fmaxf(fmaxf(s[1][0], s[1][1]), fmaxf(s[1][2], s[1][3]));
      float t2a = fmaxf(fmaxf(s[2][0], s[2][1]), fmaxf(s[2][2], s[2][3]));
      float t3a = fmaxf(fmaxf(s[3][0], s[3][1]), fmaxf(s[3][2], s[3][3]));
      float pmax = fmaxf(fmaxf(t0a, t1a), fmaxf(t2a, t3a));
      pmax = fmaxf(pmax, __shfl_xor(pmax, 16));
      pmax = fmaxf(pmax, __shfl_xor(pmax, 32));

      if (!__all(pmax <= m)) {
        const float mnew = fmaxf(m, pmax);
        const float fct = __builtin_amdgcn_exp2f(m - mnew);
        m = mnew;
        l *= fct;
#pragma unroll
        for (int r = 0; r < 4; ++r) {
          const float fr = __shfl(fct, lg * 4 + r);
#pragma unroll
          for (int nf = 0; nf < 4; ++nf) o_acc[nf][r] *= fr;
        }
      }

      float p[4][4];
#pragma unroll
      for (int nf = 0; nf < 4; ++nf)
#pragma unroll
        for (int r = 0; r < 4; ++r) p[nf][r] = __builtin_amdgcn_exp2f(s[nf][r] - m);
      float s0a = (p[0][0] + p[0][1]) + (p[0][2] + p[0][3]);
      float s1a = (p[1][0] + p[1][1]) + (p[1][2] + p[1][3]);
      float s2a = (p[2][0] + p[2][1]) + (p[2][2] + p[2][3]);
      float s3a = (p[3][0] + p[3][1]) + (p[3][2] + p[3][3]);
      float psum = (s0a + s1a) + (s2a + s3a);
      psum += __shfl_xor(psum, 16);
      psum += __shfl_xor(psum, 32);
      l += psum;

#pragma unroll
      for (int nf = 0; nf < 4; ++nf) {
        u16x4 pk;
        pk[0] = f2bf(p[nf][0]); pk[1] = f2bf(p[nf][1]);
        pk[2] = f2bf(p[nf][2]); pk[3] = f2bf(p[nf][3]);
        *(u16x4*)&lP[(w * 2048 + l15 * 128 + ((nf * 32 + lg * 8) ^ ((l15 & 7) << 4))) >> 1] = pk;
      }

      __builtin_amdgcn_s_setprio(1);
#pragma unroll
      for (int sj = 0; sj < 2; ++sj) {
        bf16x8 ap = *(const bf16x8*)&lP[(w * 2048 + l15 * 128 + ((sj * 64 + lg * 16) ^ ((l15 & 7) << 4))) >> 1];
#pragma unroll
        for (int nf = 0; nf < 4; ++nf) {
          const int d = nf * 16 + l15;
          bf16x8 bv = *(const bf16x8*)&Vc[(d * 128 + ((sj * 64 + lg * 16) ^ ((d & 7) << 4))) >> 1];
          o_acc[nf] = __builtin_amdgcn_mfma_f32_16x16x32_bf16(ap, bv, o_acc[nf], 0, 0, 0);
        }
      }
      __builtin_amdgcn_s_setprio(0);
    }

#pragma unroll
    for (int r = 0; r < 4; ++r) {
      const float li = __builtin_amdgcn_rcpf(__shfl(l, lg * 4 + r));
      const int row = q0 + w * 16 + lg * 4 + r;
#pragma unroll
      for (int nf = 0; nf < 4; ++nf) {
        const int col = h * D + nf * 16 + l15;
        y[((size_t)b * T + row) * C + col] = f2bf(o_acc[nf][r] * li);
      }
    }
  }
}

extern "C" void kernel_launch(void* const* d_in, const int* in_sizes, int n_in,
                              void* d_out, int out_size, void* d_ws, size_t ws_size,
                              hipStream_t stream) {
  const float* x = (const float*)d_in[0];
  const float* Wqkv = (const float*)d_in[1];
  const float* Wproj = (const float*)d_in[2];
  float* out = (float*)d_out;

  constexpr int B = 2, T = 2048, C = 1024, C3 = 3072, H = 16, D = 64;
  constexpr int M = B * T;  // 4096

  u16* xb = (u16*)d_ws;                       // M*C
  u16* wqkvb = xb + (size_t)M * C;            // C3*C
  u16* wprojb = wqkvb + (size_t)C3 * C;       // C*C
  u16* qkvb = wprojb + (size_t)C * C;         // M*C3 (v-part unused)
  u16* vtb = qkvb + (size_t)M * C3;           // B*H*D*T = M*C
  u16* yb = vtb + (size_t)M * C;              // M*C

  constexpr int n1 = (M * C) / 4, n2 = (C3 * C) / 4, n3 = (C * C) / 4;
  cvt3_f32_bf16<<<dim3((n1 + n2 + n3 + 255) / 256), 256, 0, stream>>>(
      x, Wqkv, Wproj, xb, n1, n2, n3);

  gemm256<1, 1><<<dim3((C3 / 256) * (M / 256)), 512, 0, stream>>>(
      xb, wqkvb, qkvb, vtb, M, C3, C);
  attn_fwd<<<dim3(512), 256, 0, stream>>>(qkvb, vtb, yb);
  gemm_nt<0, 0><<<dim3((C / 128) * (M / 128)), 256, 0, stream>>>(
      yb, wprojb, out, nullptr, M, C, C, M / 128);
}

// Round 14
// 112.849 us; speedup vs baseline: 1.0359x; 1.0359x over previous
//
#include <hip/hip_runtime.h>

typedef unsigned short u16;
typedef float f32x4 __attribute__((ext_vector_type(4)));
typedef __bf16 bf16x8 __attribute__((ext_vector_type(8)));
typedef unsigned int u32x4 __attribute__((ext_vector_type(4)));
typedef u16 u16x4 __attribute__((ext_vector_type(4)));
typedef u16 u16x8 __attribute__((ext_vector_type(8)));

static __device__ __forceinline__ u16 f2bf(float f) {
  union { __bf16 h; u16 u; } c;
  c.h = (__bf16)f;
  return c.u;
}

static __device__ __forceinline__ void gload_lds16(const void* g, void* l) {
  __builtin_amdgcn_global_load_lds(
      (const __attribute__((address_space(1))) unsigned int*)g,
      (__attribute__((address_space(3))) unsigned int*)l, 16, 0, 0);
}

// ---------------- fused fp32 -> bf16 convert ----------------
__global__ __launch_bounds__(256) void cvt3_f32_bf16(const float* __restrict__ a,
                                                     const float* __restrict__ bb,
                                                     const float* __restrict__ cc,
                                                     u16* __restrict__ out,
                                                     int n1, int n2, int n3) {
  int i = blockIdx.x * 256 + threadIdx.x;
  const float* src;
  int j = i;
  if (i < n1) { src = a; }
  else if (i < n1 + n2) { src = bb; j = i - n1; }
  else { src = cc; j = i - n1 - n2; if (j >= n3) return; }
  f32x4 v = *((const f32x4*)src + j);
  u16x4 o;
  o[0] = f2bf(v[0]); o[1] = f2bf(v[1]); o[2] = f2bf(v[2]); o[3] = f2bf(v[3]);
  *((u16x4*)out + i) = o;
}

// ---------------- 128x128 GEMM (proven m97-structure) ----------------
// XCD-aware 1D decode. FUSE_VT: v-panels (bn>=2048) write vt[bh][d][t] directly.
template<int OUT_BF16, int FUSE_VT>
__global__ __launch_bounds__(256) void gemm_nt(const u16* __restrict__ A,
                                               const u16* __restrict__ B,
                                               void* __restrict__ Cp,
                                               u16* __restrict__ vt,
                                               int M, int N, int K, int gy) {
  __shared__ __align__(16) u16 lA[128 * 64];
  __shared__ __align__(16) u16 lB[128 * 64];
  const int tid = threadIdx.x;
  const int lane = tid & 63;
  const int wave = tid >> 6;
  const int wm = wave >> 1, wn = wave & 1;
  const int l15 = lane & 15, lg = lane >> 4;

  const int bid = blockIdx.x;
  const int xcd = bid & 7, s = bid >> 3;
  const int pnx = (N >> 7) >> 3;
  const int bm = (s % gy) * 128;
  const int bn = (xcd * pnx + s / gy) * 128;

  f32x4 acc[4][4];
#pragma unroll
  for (int i = 0; i < 4; ++i)
#pragma unroll
    for (int j = 0; j < 4; ++j) acc[i][j] = (f32x4){0.f, 0.f, 0.f, 0.f};

  const u16* Ag[4];
  const u16* Bg[4];
#pragma unroll
  for (int it = 0; it < 4; ++it) {
    const int ss = it * 256 + tid;
    const int row = ss >> 3, g = ss & 7;
    const int gsw = g ^ (row & 7);
    Ag[it] = A + (size_t)(bm + row) * K + gsw * 8;
    Bg[it] = B + (size_t)(bn + row) * K + gsw * 8;
  }

  for (int k0 = 0; k0 < K; k0 += 64) {
#pragma unroll
    for (int it = 0; it < 4; ++it) {
      gload_lds16(Ag[it] + k0, (u16*)lA + (size_t)(it * 256 + tid) * 8);
      gload_lds16(Bg[it] + k0, (u16*)lB + (size_t)(it * 256 + tid) * 8);
    }
    __syncthreads();
#pragma unroll
    for (int kk = 0; kk < 2; ++kk) {
      bf16x8 af[4], bfv[4];
#pragma unroll
      for (int mf = 0; mf < 4; ++mf) {
        const int row = wm * 64 + mf * 16 + l15;
        af[mf] = *(const bf16x8*)((const char*)lA + row * 128 +
                                  ((kk * 64 + lg * 16) ^ ((row & 7) << 4)));
      }
#pragma unroll
      for (int nf = 0; nf < 4; ++nf) {
        const int row = wn * 64 + nf * 16 + l15;
        bfv[nf] = *(const bf16x8*)((const char*)lB + row * 128 +
                                   ((kk * 64 + lg * 16) ^ ((row & 7) << 4)));
      }
#pragma unroll
      for (int mf = 0; mf < 4; ++mf)
#pragma unroll
        for (int nf = 0; nf < 4; ++nf)
          acc[mf][nf] = __builtin_amdgcn_mfma_f32_16x16x32_bf16(af[mf], bfv[nf], acc[mf][nf], 0, 0, 0);
    }
    __syncthreads();
  }

  if (FUSE_VT && bn >= 2048) {
#pragma unroll
    for (int mf = 0; mf < 4; ++mf) {
      const int row0 = bm + wm * 64 + mf * 16 + lg * 4;
      const int b = row0 >> 11, t0 = row0 & 2047;
#pragma unroll
      for (int nf = 0; nf < 4; ++nf) {
        const int colv = bn - 2048 + wn * 64 + nf * 16 + l15;
        const int h = colv >> 6, d = colv & 63;
        u16x4 pk;
        pk[0] = f2bf(acc[mf][nf][0]); pk[1] = f2bf(acc[mf][nf][1]);
        pk[2] = f2bf(acc[mf][nf][2]); pk[3] = f2bf(acc[mf][nf][3]);
        *(u16x4*)&vt[((size_t)((b * 16 + h) * 64 + d)) * 2048 + t0] = pk;
      }
    }
  } else {
#pragma unroll
    for (int mf = 0; mf < 4; ++mf) {
#pragma unroll
      for (int r = 0; r < 4; ++r) {
        const int row = bm + wm * 64 + mf * 16 + lg * 4 + r;
#pragma unroll
        for (int nf = 0; nf < 4; ++nf) {
          const int col = bn + wn * 64 + nf * 16 + l15;
          const float v = acc[mf][nf][r];
          if (OUT_BF16) ((u16*)Cp)[(size_t)row * N + col] = f2bf(v);
          else          ((float*)Cp)[(size_t)row * N + col] = v;
        }
      }
    }
  }
}

// ---------------- flash attention fwd (causal), QBLK=128 / 8 waves ----------------
// Per-wave body identical to the proven R9 kernel (16 q-rows/wave, KVBLK=64,
// swapped QK^T, THR=0 defer-max, dbuf K/V, 2-deep prefetch). 8 waves share each
// staged tile; paired 128-row q-tiles (pi, 15-pi) -> uniform 34 kv-iters/block;
// 256 blocks (1/CU, 8 waves): barrier-iters/CU 66 -> 34, staging insts halved.
__global__ __launch_bounds__(512) void attn_fwd(const u16* __restrict__ qkv,
                                                const u16* __restrict__ vt,
                                                u16* __restrict__ y) {
  constexpr int T = 2048, C = 1024, C3 = 3072, D = 64;
  __shared__ __align__(16) u16 lK[2][64 * 64];
  __shared__ __align__(16) u16 lV[2][64 * 64];
  __shared__ __align__(16) u16 lP[8 * 16 * 64];
  const int tid = threadIdx.x, lane = tid & 63, w = tid >> 6;  // w in [0,8)
  const int l15 = lane & 15, lg = lane >> 4;

  // decode: 256 blocks; xcd hosts bh in [4c,4c+4); pi in [0,8) pairs with 15-pi
  const int bid = blockIdx.x;
  const int xcd = bid & 7, slot = bid >> 3;
  const int bh = xcd * 4 + (slot >> 3);
  const int pi = slot & 7;
  const int b = bh >> 4, h = bh & 15;

  // staging: ONE 16B chunk per thread per tile (512 thr x 16B = 8KB = 64x64 bf16)
  const int r0 = tid >> 3, off0 = (tid & 7) * 8;
  const int sb0 = (off0 * 2) ^ ((r0 & 7) << 4);
  const u16* Kbase = qkv + (size_t)b * T * C3 + C + h * D;
  const u16* Vbase = vt + (size_t)bh * D * T;
  char* lPb = (char*)lP + w * 2048;

  const float qscale = 0.125f * 1.44269504088896f;  // scale * log2(e)

#pragma unroll 1
  for (int qi = 0; qi < 2; ++qi) {
    const int qt = (qi == 0) ? pi : (15 - pi);   // 128-row tile index
    const int q0 = qt * 128;
    const int nkt = 2 * qt + 2;                  // kv tiles of 64
    const int qrow = q0 + w * 16 + l15;          // this lane's global q row

    const size_t qoff = ((size_t)b * T + qrow) * C3 + h * D;
    const bf16x8 aq0 = *(const bf16x8*)&qkv[qoff + lg * 8];
    const bf16x8 aq1 = *(const bf16x8*)&qkv[qoff + 32 + lg * 8];

    float m = -1.0e30f, l = 0.f;
    f32x4 o_acc[4];
#pragma unroll
    for (int nf = 0; nf < 4; ++nf) o_acc[nf] = (f32x4){0.f, 0.f, 0.f, 0.f};

    // prologue: tile 0 -> regs; drain prev pass readers; -> buf0
    u32x4 rk0 = *(const u32x4*)(Kbase + (size_t)r0 * C3 + off0);
    u32x4 rv0 = *(const u32x4*)(Vbase + (size_t)r0 * T + off0);
    __syncthreads();
    *(u32x4*)&lK[0][(r0 * 128 + sb0) >> 1] = rk0;
    *(u32x4*)&lV[0][(r0 * 128 + sb0) >> 1] = rv0;
    if (nkt > 1) {
      rk0 = *(const u32x4*)(Kbase + (size_t)(64 + r0) * C3 + off0);
      rv0 = *(const u32x4*)(Vbase + (size_t)r0 * T + 64 + off0);
    }

    for (int kt = 0; kt < nkt; ++kt) {
      const int cur = kt & 1;
      __syncthreads();  // buf[cur] visible; buf[cur^1] readers drained
      if (kt < nkt - 1) {
        *(u32x4*)&lK[cur ^ 1][(r0 * 128 + sb0) >> 1] = rk0;
        *(u32x4*)&lV[cur ^ 1][(r0 * 128 + sb0) >> 1] = rv0;
        if (kt + 1 < nkt - 1) {
          const int kn = (kt + 2) * 64;
          rk0 = *(const u32x4*)(Kbase + (size_t)(kn + r0) * C3 + off0);
          rv0 = *(const u32x4*)(Vbase + (size_t)r0 * T + kn + off0);
        }
      }
      const u16* Kc = lK[cur];
      const u16* Vc = lV[cur];

      // S^T = K Q^T (lane owns q-row qrow; s holds kv = kt*64 + nf*16+lg*4+r)
      f32x4 s[4];
#pragma unroll
      for (int nf = 0; nf < 4; ++nf) s[nf] = (f32x4){0.f, 0.f, 0.f, 0.f};
      __builtin_amdgcn_s_setprio(1);
#pragma unroll
      for (int nf = 0; nf < 4; ++nf) {
        const int row = nf * 16 + l15;
        const int x = (row & 7) << 4;
        bf16x8 bk0 = *(const bf16x8*)&Kc[(row * 128 + ((lg * 16) ^ x)) >> 1];
        bf16x8 bk1 = *(const bf16x8*)&Kc[(row * 128 + ((64 + lg * 16) ^ x)) >> 1];
        s[nf] = __builtin_amdgcn_mfma_f32_16x16x32_bf16(bk0, aq0, s[nf], 0, 0, 0);
        s[nf] = __builtin_amdgcn_mfma_f32_16x16x32_bf16(bk1, aq1, s[nf], 0, 0, 0);
      }
      __builtin_amdgcn_s_setprio(0);

      // scale (+ causal mask only on the last two kv tiles; earlier tiles can't cross diag)
      if (kt >= 2 * qt) {
        const int kb = kt * 64;
#pragma unroll
        for (int nf = 0; nf < 4; ++nf)
#pragma unroll
          for (int r = 0; r < 4; ++r) {
            float v = s[nf][r] * qscale;
            if (kb + nf * 16 + lg * 4 + r > qrow) v = -1.0e30f;
            s[nf][r] = v;
          }
      } else {
#pragma unroll
        for (int nf = 0; nf < 4; ++nf)
#pragma unroll
          for (int r = 0; r < 4; ++r) s[nf][r] *= qscale;
      }

      float t0a = fmaxf(fmaxf(s[0][0], s[0][1]), fmaxf(s[0][2], s[0][3]));
      float t1a = fmaxf(fmaxf(s[1][0], s[1][1]), fmaxf(s[1][2], s[1][3]));
      float t2a = fmaxf(fmaxf(s[2][0], s[2][1]), fmaxf(s[2][2], s[2][3]));
      float t3a = fmaxf(fmaxf(s[3][0], s[3][1]), fmaxf(s[3][2], s[3][3]));
      float pmax = fmaxf(fmaxf(t0a, t1a), fmaxf(t2a, t3a));
      pmax = fmaxf(pmax, __shfl_xor(pmax, 16));
      pmax = fmaxf(pmax, __shfl_xor(pmax, 32));

      if (!__all(pmax <= m)) {
        const float mnew = fmaxf(m, pmax);
        const float fct = __builtin_amdgcn_exp2f(m - mnew);
        m = mnew;
        l *= fct;
#pragma unroll
        for (int r = 0; r < 4; ++r) {
          const float fr = __shfl(fct, lg * 4 + r);
#pragma unroll
          for (int nf = 0; nf < 4; ++nf) o_acc[nf][r] *= fr;
        }
      }

      float p[4][4];
#pragma unroll
      for (int nf = 0; nf < 4; ++nf)
#pragma unroll
        for (int r = 0; r < 4; ++r) p[nf][r] = __builtin_amdgcn_exp2f(s[nf][r] - m);
      float s0a = (p[0][0] + p[0][1]) + (p[0][2] + p[0][3]);
      float s1a = (p[1][0] + p[1][1]) + (p[1][2] + p[1][3]);
      float s2a = (p[2][0] + p[2][1]) + (p[2][2] + p[2][3]);
      float s3a = (p[3][0] + p[3][1]) + (p[3][2] + p[3][3]);
      float psum = (s0a + s1a) + (s2a + s3a);
      psum += __shfl_xor(psum, 16);
      psum += __shfl_xor(psum, 32);
      l += psum;

      // P -> per-wave LDS region (packed b64, swizzled); same-wave RAW, DS in-order
#pragma unroll
      for (int nf = 0; nf < 4; ++nf) {
        u16x4 pk;
        pk[0] = f2bf(p[nf][0]); pk[1] = f2bf(p[nf][1]);
        pk[2] = f2bf(p[nf][2]); pk[3] = f2bf(p[nf][3]);
        *(u16x4*)(lPb + l15 * 128 + ((nf * 32 + lg * 8) ^ ((l15 & 7) << 4))) = pk;
      }

      // O += P V
      __builtin_amdgcn_s_setprio(1);
#pragma unroll
      for (int sj = 0; sj < 2; ++sj) {
        bf16x8 ap = *(const bf16x8*)(lPb + l15 * 128 + ((sj * 64 + lg * 16) ^ ((l15 & 7) << 4)));
#pragma unroll
        for (int nf = 0; nf < 4; ++nf) {
          const int d = nf * 16 + l15;
          bf16x8 bv = *(const bf16x8*)&Vc[(d * 128 + ((sj * 64 + lg * 16) ^ ((d & 7) << 4))) >> 1];
          o_acc[nf] = __builtin_amdgcn_mfma_f32_16x16x32_bf16(ap, bv, o_acc[nf], 0, 0, 0);
        }
      }
      __builtin_amdgcn_s_setprio(0);
    }

    // epilogue
#pragma unroll
    for (int r = 0; r < 4; ++r) {
      const float li = __builtin_amdgcn_rcpf(__shfl(l, lg * 4 + r));
      const int row = q0 + w * 16 + lg * 4 + r;
#pragma unroll
      for (int nf = 0; nf < 4; ++nf) {
        const int col = h * D + nf * 16 + l15;
        y[((size_t)b * T + row) * C + col] = f2bf(o_acc[nf][r] * li);
      }
    }
  }
}

extern "C" void kernel_launch(void* const* d_in, const int* in_sizes, int n_in,
                              void* d_out, int out_size, void* d_ws, size_t ws_size,
                              hipStream_t stream) {
  const float* x = (const float*)d_in[0];
  const float* Wqkv = (const float*)d_in[1];
  const float* Wproj = (const float*)d_in[2];
  float* out = (float*)d_out;

  constexpr int B = 2, T = 2048, C = 1024, C3 = 3072, H = 16, D = 64;
  constexpr int M = B * T;  // 4096

  u16* xb = (u16*)d_ws;                       // M*C
  u16* wqkvb = xb + (size_t)M * C;            // C3*C
  u16* wprojb = wqkvb + (size_t)C3 * C;       // C*C
  u16* qkvb = wprojb + (size_t)C * C;         // M*C3 (v-part unused)
  u16* vtb = qkvb + (size_t)M * C3;           // B*H*D*T = M*C
  u16* yb = vtb + (size_t)M * C;              // M*C

  constexpr int n1 = (M * C) / 4, n2 = (C3 * C) / 4, n3 = (C * C) / 4;
  cvt3_f32_bf16<<<dim3((n1 + n2 + n3 + 255) / 256), 256, 0, stream>>>(
      x, Wqkv, Wproj, xb, n1, n2, n3);

  gemm_nt<1, 1><<<dim3((C3 / 128) * (M / 128)), 256, 0, stream>>>(
      xb, wqkvb, qkvb, vtb, M, C3, C, M / 128);
  attn_fwd<<<dim3(256), 512, 0, stream>>>(qkvb, vtb, yb);
  gemm_nt<0, 0><<<dim3((C / 128) * (M / 128)), 256, 0, stream>>>(
      yb, wprojb, out, nullptr, M, C, C, M / 128);
}

// Round 15
// 110.807 us; speedup vs baseline: 1.0550x; 1.0184x over previous
//
#include <hip/hip_runtime.h>

typedef unsigned short u16;
typedef float f32x4 __attribute__((ext_vector_type(4)));
typedef __bf16 bf16x8 __attribute__((ext_vector_type(8)));
typedef unsigned int u32x4 __attribute__((ext_vector_type(4)));
typedef u16 u16x4 __attribute__((ext_vector_type(4)));
typedef u16 u16x8 __attribute__((ext_vector_type(8)));

static __device__ __forceinline__ u16 f2bf(float f) {
  union { __bf16 h; u16 u; } c;
  c.h = (__bf16)f;
  return c.u;
}
static __device__ __forceinline__ float bf2f(u16 u) {
  union { unsigned u; float f; } c;
  c.u = ((unsigned)u) << 16;
  return c.f;
}

static __device__ __forceinline__ void gload_lds16(const void* g, void* l) {
  __builtin_amdgcn_global_load_lds(
      (const __attribute__((address_space(1))) unsigned int*)g,
      (__attribute__((address_space(3))) unsigned int*)l, 16, 0, 0);
}

// ---------------- fused fp32 -> bf16 convert ----------------
__global__ __launch_bounds__(256) void cvt3_f32_bf16(const float* __restrict__ a,
                                                     const float* __restrict__ bb,
                                                     const float* __restrict__ cc,
                                                     u16* __restrict__ out,
                                                     int n1, int n2, int n3) {
  int i = blockIdx.x * 256 + threadIdx.x;
  const float* src;
  int j = i;
  if (i < n1) { src = a; }
  else if (i < n1 + n2) { src = bb; j = i - n1; }
  else { src = cc; j = i - n1 - n2; if (j >= n3) return; }
  f32x4 v = *((const f32x4*)src + j);
  u16x4 o;
  o[0] = f2bf(v[0]); o[1] = f2bf(v[1]); o[2] = f2bf(v[2]); o[3] = f2bf(v[3]);
  *((u16x4*)out + i) = o;
}

// ---------------- 128x128 GEMM (proven m97-structure) ----------------
// XCD-aware 1D decode. FUSE_VT: v-panels (bn>=2048) write vt[bh][d][t] directly.
template<int OUT_BF16, int FUSE_VT>
__global__ __launch_bounds__(256) void gemm_nt(const u16* __restrict__ A,
                                               const u16* __restrict__ B,
                                               void* __restrict__ Cp,
                                               u16* __restrict__ vt,
                                               int M, int N, int K, int gy) {
  __shared__ __align__(16) u16 lA[128 * 64];
  __shared__ __align__(16) u16 lB[128 * 64];
  const int tid = threadIdx.x;
  const int lane = tid & 63;
  const int wave = tid >> 6;
  const int wm = wave >> 1, wn = wave & 1;
  const int l15 = lane & 15, lg = lane >> 4;

  const int bid = blockIdx.x;
  const int xcd = bid & 7, s = bid >> 3;
  const int pnx = (N >> 7) >> 3;
  const int bm = (s % gy) * 128;
  const int bn = (xcd * pnx + s / gy) * 128;

  f32x4 acc[4][4];
#pragma unroll
  for (int i = 0; i < 4; ++i)
#pragma unroll
    for (int j = 0; j < 4; ++j) acc[i][j] = (f32x4){0.f, 0.f, 0.f, 0.f};

  const u16* Ag[4];
  const u16* Bg[4];
#pragma unroll
  for (int it = 0; it < 4; ++it) {
    const int ss = it * 256 + tid;
    const int row = ss >> 3, g = ss & 7;
    const int gsw = g ^ (row & 7);
    Ag[it] = A + (size_t)(bm + row) * K + gsw * 8;
    Bg[it] = B + (size_t)(bn + row) * K + gsw * 8;
  }

  for (int k0 = 0; k0 < K; k0 += 64) {
#pragma unroll
    for (int it = 0; it < 4; ++it) {
      gload_lds16(Ag[it] + k0, (u16*)lA + (size_t)(it * 256 + tid) * 8);
      gload_lds16(Bg[it] + k0, (u16*)lB + (size_t)(it * 256 + tid) * 8);
    }
    __syncthreads();
#pragma unroll
    for (int kk = 0; kk < 2; ++kk) {
      bf16x8 af[4], bfv[4];
#pragma unroll
      for (int mf = 0; mf < 4; ++mf) {
        const int row = wm * 64 + mf * 16 + l15;
        af[mf] = *(const bf16x8*)((const char*)lA + row * 128 +
                                  ((kk * 64 + lg * 16) ^ ((row & 7) << 4)));
      }
#pragma unroll
      for (int nf = 0; nf < 4; ++nf) {
        const int row = wn * 64 + nf * 16 + l15;
        bfv[nf] = *(const bf16x8*)((const char*)lB + row * 128 +
                                   ((kk * 64 + lg * 16) ^ ((row & 7) << 4)));
      }
#pragma unroll
      for (int mf = 0; mf < 4; ++mf)
#pragma unroll
        for (int nf = 0; nf < 4; ++nf)
          acc[mf][nf] = __builtin_amdgcn_mfma_f32_16x16x32_bf16(af[mf], bfv[nf], acc[mf][nf], 0, 0, 0);
    }
    __syncthreads();
  }

  if (FUSE_VT && bn >= 2048) {
#pragma unroll
    for (int mf = 0; mf < 4; ++mf) {
      const int row0 = bm + wm * 64 + mf * 16 + lg * 4;
      const int b = row0 >> 11, t0 = row0 & 2047;
#pragma unroll
      for (int nf = 0; nf < 4; ++nf) {
        const int colv = bn - 2048 + wn * 64 + nf * 16 + l15;
        const int h = colv >> 6, d = colv & 63;
        u16x4 pk;
        pk[0] = f2bf(acc[mf][nf][0]); pk[1] = f2bf(acc[mf][nf][1]);
        pk[2] = f2bf(acc[mf][nf][2]); pk[3] = f2bf(acc[mf][nf][3]);
        *(u16x4*)&vt[((size_t)((b * 16 + h) * 64 + d)) * 2048 + t0] = pk;
      }
    }
  } else {
#pragma unroll
    for (int mf = 0; mf < 4; ++mf) {
#pragma unroll
      for (int r = 0; r < 4; ++r) {
        const int row = bm + wm * 64 + mf * 16 + lg * 4 + r;
#pragma unroll
        for (int nf = 0; nf < 4; ++nf) {
          const int col = bn + wn * 64 + nf * 16 + l15;
          const float v = acc[mf][nf][r];
          if (OUT_BF16) ((u16*)Cp)[(size_t)row * N + col] = f2bf(v);
          else          ((float*)Cp)[(size_t)row * N + col] = v;
        }
      }
    }
  }
}

// ---------------- flash attention fwd (causal), QBLK=128 / 8 waves, kv-split ----------------
// Per-wave body = proven R13 kernel. Block (bh, pi, hf): q-passes qt=pi and
// qt=15-pi, kv-half hf of each -> (pi+1)+(16-pi) = 17 iters for EVERY block.
// 512 blocks x 8 waves = 2 blocks/CU (96KB LDS), uniform lifetimes -> no drain,
// no dispatch-mapping assumption. Writes l-normalized bf16 partial O + (m,l);
// merge_o combines the two halves.
__global__ __launch_bounds__(512) void attn_fwd(const u16* __restrict__ qkv,
                                                const u16* __restrict__ vt,
                                                u16* __restrict__ po,
                                                float* __restrict__ mlf) {
  constexpr int T = 2048, C = 1024, C3 = 3072, D = 64;
  __shared__ __align__(16) u16 lK[2][64 * 64];
  __shared__ __align__(16) u16 lV[2][64 * 64];
  __shared__ __align__(16) u16 lP[8 * 16 * 64];
  const int tid = threadIdx.x, lane = tid & 63, w = tid >> 6;  // w in [0,8)
  const int l15 = lane & 15, lg = lane >> 4;

  // decode: 512 blocks; xcd hosts bh in [4c,4c+4); pi in [0,8); hf in {0,1}
  const int bid = blockIdx.x;
  const int xcd = bid & 7, slot = bid >> 3;          // slot in [0,64)
  const int bh = xcd * 4 + (slot >> 4);
  const int rem = slot & 15;
  const int pi = rem >> 1, hf = rem & 1;
  const int b = bh >> 4, h = bh & 15;

  // staging: ONE 16B chunk per thread per tile
  const int r0 = tid >> 3, off0 = (tid & 7) * 8;
  const int sb0 = (off0 * 2) ^ ((r0 & 7) << 4);
  const u16* Kbase = qkv + (size_t)b * T * C3 + C + h * D;
  const u16* Vbase = vt + (size_t)bh * D * T;
  char* lPb = (char*)lP + w * 2048;

  const float qscale = 0.125f * 1.44269504088896f;  // scale * log2(e)

#pragma unroll 1
  for (int qi = 0; qi < 2; ++qi) {
    const int qt = (qi == 0) ? pi : (15 - pi);   // 128-row q-tile index
    const int q0 = qt * 128;
    const int kts = hf ? (qt + 1) : 0;           // kv-half ranges, each qt+1 tiles
    const int kte = hf ? (2 * qt + 2) : (qt + 1);
    const int nit = kte - kts;
    const int qrow = q0 + w * 16 + l15;

    const size_t qoff = ((size_t)b * T + qrow) * C3 + h * D;
    const bf16x8 aq0 = *(const bf16x8*)&qkv[qoff + lg * 8];
    const bf16x8 aq1 = *(const bf16x8*)&qkv[qoff + 32 + lg * 8];

    float m = -1.0e30f, l = 0.f;
    f32x4 o_acc[4];
#pragma unroll
    for (int nf = 0; nf < 4; ++nf) o_acc[nf] = (f32x4){0.f, 0.f, 0.f, 0.f};

    // prologue: tile kts -> regs; drain prev pass readers; -> buf0
    u32x4 rk0 = *(const u32x4*)(Kbase + (size_t)(kts * 64 + r0) * C3 + off0);
    u32x4 rv0 = *(const u32x4*)(Vbase + (size_t)r0 * T + kts * 64 + off0);
    __syncthreads();
    *(u32x4*)&lK[0][(r0 * 128 + sb0) >> 1] = rk0;
    *(u32x4*)&lV[0][(r0 * 128 + sb0) >> 1] = rv0;
    if (nit > 1) {
      rk0 = *(const u32x4*)(Kbase + (size_t)((kts + 1) * 64 + r0) * C3 + off0);
      rv0 = *(const u32x4*)(Vbase + (size_t)r0 * T + (kts + 1) * 64 + off0);
    }

    for (int i = 0; i < nit; ++i) {
      const int kt = kts + i;
      const int cur = i & 1;
      __syncthreads();  // buf[cur] visible; buf[cur^1] readers drained
      if (i < nit - 1) {
        *(u32x4*)&lK[cur ^ 1][(r0 * 128 + sb0) >> 1] = rk0;
        *(u32x4*)&lV[cur ^ 1][(r0 * 128 + sb0) >> 1] = rv0;
        if (i + 1 < nit - 1) {
          const int kn = (kt + 2) * 64;
          rk0 = *(const u32x4*)(Kbase + (size_t)(kn + r0) * C3 + off0);
          rv0 = *(const u32x4*)(Vbase + (size_t)r0 * T + kn + off0);
        }
      }
      const u16* Kc = lK[cur];
      const u16* Vc = lV[cur];

      // S^T = K Q^T (lane owns q-row qrow; s holds kv = kt*64 + nf*16+lg*4+r)
      f32x4 s[4];
#pragma unroll
      for (int nf = 0; nf < 4; ++nf) s[nf] = (f32x4){0.f, 0.f, 0.f, 0.f};
      __builtin_amdgcn_s_setprio(1);
#pragma unroll
      for (int nf = 0; nf < 4; ++nf) {
        const int row = nf * 16 + l15;
        const int x = (row & 7) << 4;
        bf16x8 bk0 = *(const bf16x8*)&Kc[(row * 128 + ((lg * 16) ^ x)) >> 1];
        bf16x8 bk1 = *(const bf16x8*)&Kc[(row * 128 + ((64 + lg * 16) ^ x)) >> 1];
        s[nf] = __builtin_amdgcn_mfma_f32_16x16x32_bf16(bk0, aq0, s[nf], 0, 0, 0);
        s[nf] = __builtin_amdgcn_mfma_f32_16x16x32_bf16(bk1, aq1, s[nf], 0, 0, 0);
      }
      __builtin_amdgcn_s_setprio(0);

      // scale (+ causal mask only when tile can cross the diagonal)
      if (kt >= 2 * qt) {
        const int kb = kt * 64;
#pragma unroll
        for (int nf = 0; nf < 4; ++nf)
#pragma unroll
          for (int r = 0; r < 4; ++r) {
            float v = s[nf][r] * qscale;
            if (kb + nf * 16 + lg * 4 + r > qrow) v = -1.0e30f;
            s[nf][r] = v;
          }
      } else {
#pragma unroll
        for (int nf = 0; nf < 4; ++nf)
#pragma unroll
          for (int r = 0; r < 4; ++r) s[nf][r] *= qscale;
      }

      float t0a = fmaxf(fmaxf(s[0][0], s[0][1]), fmaxf(s[0][2], s[0][3]));
      float t1a = fmaxf(fmaxf(s[1][0], s[1][1]), fmaxf(s[1][2], s[1][3]));
      float t2a = fmaxf(fmaxf(s[2][0], s[2][1]), fmaxf(s[2][2], s[2][3]));
      float t3a = fmaxf(fmaxf(s[3][0], s[3][1]), fmaxf(s[3][2], s[3][3]));
      float pmax = fmaxf(fmaxf(t0a, t1a), fmaxf(t2a, t3a));
      pmax = fmaxf(pmax, __shfl_xor(pmax, 16));
      pmax = fmaxf(pmax, __shfl_xor(pmax, 32));

      if (!__all(pmax <= m)) {
        const float mnew = fmaxf(m, pmax);
        const float fct = __builtin_amdgcn_exp2f(m - mnew);
        m = mnew;
        l *= fct;
#pragma unroll
        for (int r = 0; r < 4; ++r) {
          const float fr = __shfl(fct, lg * 4 + r);
#pragma unroll
          for (int nf = 0; nf < 4; ++nf) o_acc[nf][r] *= fr;
        }
      }

      float p[4][4];
#pragma unroll
      for (int nf = 0; nf < 4; ++nf)
#pragma unroll
        for (int r = 0; r < 4; ++r) p[nf][r] = __builtin_amdgcn_exp2f(s[nf][r] - m);
      float s0a = (p[0][0] + p[0][1]) + (p[0][2] + p[0][3]);
      float s1a = (p[1][0] + p[1][1]) + (p[1][2] + p[1][3]);
      float s2a = (p[2][0] + p[2][1]) + (p[2][2] + p[2][3]);
      float s3a = (p[3][0] + p[3][1]) + (p[3][2] + p[3][3]);
      float psum = (s0a + s1a) + (s2a + s3a);
      psum += __shfl_xor(psum, 16);
      psum += __shfl_xor(psum, 32);
      l += psum;

      // P -> per-wave LDS region (packed b64, swizzled); same-wave RAW
#pragma unroll
      for (int nf = 0; nf < 4; ++nf) {
        u16x4 pk;
        pk[0] = f2bf(p[nf][0]); pk[1] = f2bf(p[nf][1]);
        pk[2] = f2bf(p[nf][2]); pk[3] = f2bf(p[nf][3]);
        *(u16x4*)(lPb + l15 * 128 + ((nf * 32 + lg * 8) ^ ((l15 & 7) << 4))) = pk;
      }

      // O += P V
      __builtin_amdgcn_s_setprio(1);
#pragma unroll
      for (int sj = 0; sj < 2; ++sj) {
        bf16x8 ap = *(const bf16x8*)(lPb + l15 * 128 + ((sj * 64 + lg * 16) ^ ((l15 & 7) << 4)));
#pragma unroll
        for (int nf = 0; nf < 4; ++nf) {
          const int d = nf * 16 + l15;
          bf16x8 bv = *(const bf16x8*)&Vc[(d * 128 + ((sj * 64 + lg * 16) ^ ((d & 7) << 4))) >> 1];
          o_acc[nf] = __builtin_amdgcn_mfma_f32_16x16x32_bf16(ap, bv, o_acc[nf], 0, 0, 0);
        }
      }
      __builtin_amdgcn_s_setprio(0);
    }

    // epilogue: l-normalized bf16 partial O + (m,l)
    u16* pob = po + (size_t)hf * (4096ull * 1024ull);
#pragma unroll
    for (int r = 0; r < 4; ++r) {
      const float lv = __shfl(l, lg * 4 + r);
      const float li = (lv > 0.f) ? __builtin_amdgcn_rcpf(lv) : 0.f;
      const int row = q0 + w * 16 + lg * 4 + r;
#pragma unroll
      for (int nf = 0; nf < 4; ++nf) {
        const int col = h * D + nf * 16 + l15;
        pob[((size_t)b * T + row) * C + col] = f2bf(o_acc[nf][r] * li);
      }
    }
    if (lg == 0) {
      const size_t idx = (size_t)(b * T + qrow) * 16 + h;
      float* mp = mlf + (size_t)hf * 131072ull + idx * 2;
      mp[0] = m;
      mp[1] = l;
    }
  }
}

// ---------------- merge the two kv-halves: y = w1*o1 + w2*o2 ----------------
__global__ __launch_bounds__(256) void merge_o(const u16* __restrict__ po,
                                               const float* __restrict__ mlf,
                                               u16* __restrict__ y) {
  const int gid = blockIdx.x * 256 + threadIdx.x;   // 524288 threads
  const int row = gid >> 3, d0 = (gid & 7) * 8;     // row in [0, 65536)
  const int bt = row >> 4, h = row & 15;
  const float m1 = mlf[row * 2], l1 = mlf[row * 2 + 1];
  const float m2 = mlf[131072 + row * 2], l2 = mlf[131072 + row * 2 + 1];
  const float ms = fmaxf(m1, m2);
  const float a1 = l1 * __builtin_amdgcn_exp2f(m1 - ms);
  const float a2 = l2 * __builtin_amdgcn_exp2f(m2 - ms);
  const float inv = __builtin_amdgcn_rcpf(a1 + a2);
  const float w1 = a1 * inv, w2 = a2 * inv;
  const size_t off = (size_t)bt * 1024 + h * 64 + d0;
  u16x8 p1 = *(const u16x8*)&po[off];
  u16x8 p2 = *(const u16x8*)&po[4194304ull + off];
  u16x8 o;
#pragma unroll
  for (int j = 0; j < 8; ++j) o[j] = f2bf(w1 * bf2f(p1[j]) + w2 * bf2f(p2[j]));
  *(u16x8*)&y[off] = o;
}

extern "C" void kernel_launch(void* const* d_in, const int* in_sizes, int n_in,
                              void* d_out, int out_size, void* d_ws, size_t ws_size,
                              hipStream_t stream) {
  const float* x = (const float*)d_in[0];
  const float* Wqkv = (const float*)d_in[1];
  const float* Wproj = (const float*)d_in[2];
  float* out = (float*)d_out;

  constexpr int B = 2, T = 2048, C = 1024, C3 = 3072, H = 16, D = 64;
  constexpr int M = B * T;  // 4096

  u16* xb = (u16*)d_ws;                       // M*C
  u16* wqkvb = xb + (size_t)M * C;            // C3*C
  u16* wprojb = wqkvb + (size_t)C3 * C;       // C*C
  u16* qkvb = wprojb + (size_t)C * C;         // M*C3 (v-part unused)
  u16* vtb = qkvb + (size_t)M * C3;           // B*H*D*T = M*C
  u16* yb = vtb + (size_t)M * C;              // M*C
  u16* po = yb + (size_t)M * C;               // 2 * M*C (both halves)
  float* mlf = (float*)(po + 2ull * M * C);   // 2 * 65536 * 2 floats

  constexpr int n1 = (M * C) / 4, n2 = (C3 * C) / 4, n3 = (C * C) / 4;
  cvt3_f32_bf16<<<dim3((n1 + n2 + n3 + 255) / 256), 256, 0, stream>>>(
      x, Wqkv, Wproj, xb, n1, n2, n3);

  gemm_nt<1, 1><<<dim3((C3 / 128) * (M / 128)), 256, 0, stream>>>(
      xb, wqkvb, qkvb, vtb, M, C3, C, M / 128);
  attn_fwd<<<dim3(512), 512, 0, stream>>>(qkvb, vtb, po, mlf);
  merge_o<<<dim3(2048), 256, 0, stream>>>(po, mlf, yb);
  gemm_nt<0, 0><<<dim3((C / 128) * (M / 128)), 256, 0, stream>>>(
      yb, wprojb, out, nullptr, M, C, C, M / 128);
}